// Round 1
// baseline (144.041 us; speedup 1.0000x reference)
//
#include <hip/hip_runtime.h>

// RAFT corr block: B=2, D=256, H=W=80, 4 levels, radius 4.
// Key identity: avg_pool2(corr) over spatial dims of fmap2 == corr with avg-pooled fmap2,
// so we never materialize the 6400x6400 volume.

typedef _Float16 h2 __attribute__((ext_vector_type(2)));

#define HWDIM 80
#define DCH 256

// ---------------- transpose [B,256,6400] fp32 -> [B,6400,256] f16 ----------------
__global__ __launch_bounds__(256) void transpose_f16(const float* __restrict__ src,
                                                     _Float16* __restrict__ dst) {
    __shared__ float tile[256][33];
    int bid = blockIdx.x;
    int b = bid / 200;               // 6400/32 = 200 tiles per batch
    int s0 = (bid % 200) * 32;
    int t = threadIdx.x;
    const float* sb = src + (size_t)b * DCH * (HWDIM * HWDIM);
#pragma unroll 4
    for (int k = 0; k < 32; ++k) {
        int j = t + 256 * k;
        int c = j >> 5, s = j & 31;
        tile[c][s] = sb[(size_t)c * (HWDIM * HWDIM) + s0 + s];
    }
    __syncthreads();
    _Float16* db = dst + ((size_t)b * (HWDIM * HWDIM) + s0) * DCH;
    int p = t & 127;
    int srow = t >> 7;
#pragma unroll 4
    for (int k = 0; k < 16; ++k) {
        int s = 2 * k + srow;
        h2 v;
        v[0] = (_Float16)tile[2 * p][s];
        v[1] = (_Float16)tile[2 * p + 1][s];
        *(h2*)(db + (size_t)s * DCH + 2 * p) = v;
    }
}

// ---------------- 2x2 avg pool on [B,H,W,256] f16 ----------------
__global__ __launch_bounds__(256) void pool2(const _Float16* __restrict__ src,
                                             _Float16* __restrict__ dst,
                                             int Hl, int Wl, int total) {
    int i = blockIdx.x * 256 + threadIdx.x;
    if (i >= total) return;                 // total = B*Hl*Wl*128 (h2 units)
    int c2 = i & 127;
    int xy = i >> 7;
    int x = xy % Wl;
    int y = (xy / Wl) % Hl;
    int b = xy / (Wl * Hl);
    int Ws = Wl * 2;
    const h2* s = (const h2*)src + (((size_t)(b * (2 * Hl) + 2 * y) * Ws) + 2 * x) * 128 + c2;
    h2 v00 = s[0];
    h2 v01 = s[128];
    h2 v10 = s[(size_t)Ws * 128];
    h2 v11 = s[(size_t)Ws * 128 + 128];
    float r0 = ((float)v00[0] + (float)v01[0] + (float)v10[0] + (float)v11[0]) * 0.25f;
    float r1 = ((float)v00[1] + (float)v01[1] + (float)v10[1] + (float)v11[1]) * 0.25f;
    h2 o;
    o[0] = (_Float16)r0;
    o[1] = (_Float16)r1;
    ((h2*)dst)[i] = o;
}

// ---------------- main: per-pixel correlation sampling ----------------
// block = 256 threads = 4 waves; wave L handles pyramid level L for pixel blockIdx.x.
// Within a wave: 4 taps in flight (g = lane>>4), 16 lanes per tap each covering 16 channels.
__global__ __launch_bounds__(256) void corr_sample(
    const _Float16* __restrict__ f1h,
    const _Float16* __restrict__ f20, const _Float16* __restrict__ f21,
    const _Float16* __restrict__ f22, const _Float16* __restrict__ f23,
    const float* __restrict__ coords, float* __restrict__ out) {
    __shared__ float taps[4][100];

    int n = blockIdx.x;                    // 0..12799
    int x0 = n % 80;
    int y0 = (n / 80) % 80;
    int b = n / 6400;
    int L = threadIdx.x >> 6;              // wave id == level
    int lane = threadIdx.x & 63;
    int g = lane >> 4;                     // tap slot within group of 4
    int q = lane & 15;                     // channel chunk

    float cx = coords[(((size_t)b * 2 + 0) * 80 + y0) * 80 + x0];
    float cy = coords[(((size_t)b * 2 + 1) * 80 + y0) * 80 + x0];

    // f1 fragment: channels [8q,8q+8) and [128+8q,128+8q+8)  (32B, two float4 loads)
    const float4* f1p = (const float4*)(f1h + (size_t)n * DCH);
    float4 a1 = f1p[q];
    float4 b1 = f1p[q + 16];
    const h2* a1h = (const h2*)&a1;
    const h2* b1h = (const h2*)&b1;
    // pre-convert f1 to fp32 so inner loop is pure v_fma_mix-style MACs
    float f1f[16];
#pragma unroll
    for (int u = 0; u < 4; ++u) {
        f1f[2 * u]     = (float)a1h[u][0];
        f1f[2 * u + 1] = (float)a1h[u][1];
        f1f[8 + 2 * u]     = (float)b1h[u][0];
        f1f[8 + 2 * u + 1] = (float)b1h[u][1];
    }

    float ls = 1.0f / (float)(1 << L);
    float cxl = cx * ls, cyl = cy * ls;
    float fxf = floorf(cxl), fyf = floorf(cyl);
    int X0 = (int)fxf - 4, Y0 = (int)fyf - 4;
    float fx = cxl - fxf, fy = cyl - fyf;
    int Wl = HWDIM >> L, Hl = HWDIM >> L;
    const _Float16* f2 = (L == 0 ? f20 : L == 1 ? f21 : L == 2 ? f22 : f23)
                         + (size_t)b * Wl * Hl * DCH;

    for (int grp = 0; grp < 25; ++grp) {
        int t = grp * 4 + g;               // tap 0..99
        int tx = t % 10, ty = t / 10;
        int xi = X0 + tx, yi = Y0 + ty;
        float acc = 0.f;
        if ((unsigned)xi < (unsigned)Wl && (unsigned)yi < (unsigned)Hl) {
            const float4* rp = (const float4*)(f2 + ((size_t)yi * Wl + xi) * DCH);
            float4 a2 = rp[q];
            float4 b2 = rp[q + 16];
            const h2* a2h = (const h2*)&a2;
            const h2* b2h = (const h2*)&b2;
#pragma unroll
            for (int u = 0; u < 4; ++u) {
                acc = fmaf((float)a2h[u][0], f1f[2 * u], acc);
                acc = fmaf((float)a2h[u][1], f1f[2 * u + 1], acc);
                acc = fmaf((float)b2h[u][0], f1f[8 + 2 * u], acc);
                acc = fmaf((float)b2h[u][1], f1f[8 + 2 * u + 1], acc);
            }
        }
        // reduce 16 sublanes (xor masks stay within the 16-lane group)
        acc += __shfl_xor(acc, 1);
        acc += __shfl_xor(acc, 2);
        acc += __shfl_xor(acc, 4);
        acc += __shfl_xor(acc, 8);
        if (q == 0) taps[L][t] = acc * 0.0625f;   // / sqrt(256)
    }
    __syncthreads();

    float* ob = out + (((size_t)b * 324 + L * 81) * 6400) + (size_t)y0 * 80 + x0;
    for (int k = lane; k < 81; k += 64) {
        int a = k / 9;                     // x-offset index (delta[:,0] added to x)
        int c = k % 9;                     // y-offset index
        float t00 = taps[L][c * 10 + a];
        float t01 = taps[L][c * 10 + a + 1];
        float t10 = taps[L][(c + 1) * 10 + a];
        float t11 = taps[L][(c + 1) * 10 + a + 1];
        float v = (1.f - fy) * ((1.f - fx) * t00 + fx * t01)
                + fy * ((1.f - fx) * t10 + fx * t11);
        ob[(size_t)k * 6400] = v;
    }
}

extern "C" void kernel_launch(void* const* d_in, const int* in_sizes, int n_in,
                              void* d_out, int out_size, void* d_ws, size_t ws_size,
                              hipStream_t stream) {
    const float* fmap1 = (const float*)d_in[0];
    const float* fmap2 = (const float*)d_in[1];
    const float* coords = (const float*)d_in[2];
    float* out = (float*)d_out;
    char* ws = (char*)d_ws;

    _Float16* f1h = (_Float16*)(ws);                  // 2*6400*256*2 = 6553600 B
    _Float16* f20 = (_Float16*)(ws + 6553600);        // 6553600 B
    _Float16* f21 = (_Float16*)(ws + 13107200);       // 1638400 B
    _Float16* f22 = (_Float16*)(ws + 14745600);       // 409600 B
    _Float16* f23 = (_Float16*)(ws + 15155200);       // 102400 B

    transpose_f16<<<dim3(400), dim3(256), 0, stream>>>(fmap1, f1h);
    transpose_f16<<<dim3(400), dim3(256), 0, stream>>>(fmap2, f20);
    pool2<<<dim3(1600), dim3(256), 0, stream>>>(f20, f21, 40, 40, 2 * 40 * 40 * 128);
    pool2<<<dim3(400), dim3(256), 0, stream>>>(f21, f22, 20, 20, 2 * 20 * 20 * 128);
    pool2<<<dim3(100), dim3(256), 0, stream>>>(f22, f23, 10, 10, 2 * 10 * 10 * 128);
    corr_sample<<<dim3(12800), dim3(256), 0, stream>>>(f1h, f20, f21, f22, f23, coords, out);
}